// Round 6
// baseline (902.843 us; speedup 1.0000x reference)
//
#include <hip/hip_runtime.h>
#include <hip/hip_bf16.h>

// RecNN: u = relu(contents @ W_u^T + b_u); v = u[internal] @ W_hu^T (hoisted);
// 10 levels emb = relu([emb_L|emb_R] @ W_LR^T + v + b_h).
//
// Round-6: REGISTER-DIRECT GEMM — no LDS, no barriers. For 16x16x32 MFMA,
// each lane's A and B fragment is 16 contiguous bytes of a row-major source
// row, so fragments load global->register directly. This removes the
// glds+__syncthreads+vmcnt(0) pipeline (rounds 1-5 were pinned at ~10%
// MfmaUtil by the per-k-step barrier drain; conflicts=0 in r5 proved LDS
// wasn't the limiter). Waves are fully independent: each computes a 64x64
// tile (acc[4][4]); a 256-thread block = 4 waves covering 4 n-slices of one
// m-stripe (A row re-reads hit L1/L2). Compiler software-pipelines the
// register loads (manual unroll-by-2 with two frag sets).
// A re-read x8 across N=512 -> contents pre-converted to bf16 once.

typedef unsigned short u16;
typedef __attribute__((ext_vector_type(8))) short bf16x8;
typedef __attribute__((ext_vector_type(4))) float f32x4;

__device__ __forceinline__ u16 f2b(float f) {
  union { float f; unsigned u; } c; c.f = f;
  unsigned u = c.u;
  return (u16)((u + 0x7fffu + ((u >> 16) & 1u)) >> 16);  // RNE
}

__device__ __forceinline__ float b2f(unsigned hi16) {
  union { float f; unsigned u; } c; c.u = hi16 << 16; return c.f;
}

// MODE 0: A bf16 [M][K], epilogue bias+relu                       (GEMM1)
// MODE 2: A bf16 [M][K], raw store                                (v-GEMM)
// MODE 1: A gathered [emb[c.x] | emb[c.y]] (K=1024), +v+bias+relu (levels)
// M must be a multiple of 64 (true for all calls).
template <int MODE>
__global__ __launch_bounds__(256)
void gemm_reg(const u16* __restrict__ A,
              const u16* __restrict__ embPrev,
              const int2* __restrict__ idx,
              const u16* __restrict__ vLvl,   // [M][512] bf16
              const u16* __restrict__ W,      // bf16, row stride ldb (B^T)
              int ldb,
              const float* __restrict__ bias,
              u16* __restrict__ out,          // [M][512] bf16
              int M, int K) {
  const int lane = threadIdx.x & 63;
  const int wv   = threadIdx.x >> 6;
  const int b    = blockIdx.x;
  const int m0   = (b >> 1) * 64;             // m-stripe shared by 4 waves
  const int n0   = ((b & 1) * 4 + wv) * 64;   // per-wave n-slice
  const int fm   = lane & 15;
  const int kk   = (lane >> 4) * 8;

  // Per-lane A row pointers (4 frag rows: m0 + i*16 + fm), pre-offset by kk.
  const u16* aL[4];
  const u16* aR[4];
#pragma unroll
  for (int i = 0; i < 4; i++) {
    int m = m0 + i * 16 + fm;
    if (MODE == 1) {
      int2 c = idx[m];
      aL[i] = embPrev + (size_t)c.x * 512 + kk;
      aR[i] = embPrev + (size_t)c.y * 512 + kk;
    } else {
      aL[i] = A + (size_t)m * K + kk;
    }
  }
  // Per-lane B row pointers (4 frag rows: n0 + j*16 + fm), pre-offset by kk.
  const u16* brow[4];
#pragma unroll
  for (int j = 0; j < 4; j++)
    brow[j] = W + (size_t)(n0 + j * 16 + fm) * ldb + kk;

  f32x4 acc[4][4] = {};
  bf16x8 a0[4], b0[4], a1[4], b1[4];

  auto loadA = [&](int k, bf16x8* a) {
#pragma unroll
    for (int i = 0; i < 4; i++) {
      const u16* p = (MODE == 1) ? (((k & 512) ? aR[i] : aL[i]) + (k & 511))
                                 : (aL[i] + k);
      a[i] = *(const bf16x8*)p;
    }
  };
  auto loadB = [&](int k, bf16x8* bb) {
#pragma unroll
    for (int j = 0; j < 4; j++) bb[j] = *(const bf16x8*)(brow[j] + k);
  };
  auto mf = [&](bf16x8* a, bf16x8* bb) {
#pragma unroll
    for (int i = 0; i < 4; i++)
#pragma unroll
      for (int j = 0; j < 4; j++)
        acc[i][j] = __builtin_amdgcn_mfma_f32_16x16x32_bf16(a[i], bb[j], acc[i][j], 0, 0, 0);
  };

  loadA(0, a0); loadB(0, b0);
  for (int k = 0; k < K; k += 64) {
    if (k + 32 < K) { loadA(k + 32, a1); loadB(k + 32, b1); }
    mf(a0, b0);
    if (k + 64 < K) { loadA(k + 64, a0); loadB(k + 64, b0); }
    if (k + 32 < K) mf(a1, b1);
  }

  // Epilogue: C/D layout col=lane&15, row=(lane>>4)*4+reg (m89-verified).
  const int r0 = (lane >> 4) * 4;
#pragma unroll
  for (int i = 0; i < 4; i++) {
    int mI = m0 + i * 16 + r0;
#pragma unroll
    for (int j = 0; j < 4; j++) {
      int col = n0 + j * 16 + fm;
      float bb = (MODE == 2) ? 0.f : bias[col];
#pragma unroll
      for (int r = 0; r < 4; r++) {
        int m = mI + r;
        float v = acc[i][j][r] + bb;
        if (MODE == 1) v += b2f(vLvl[(size_t)m * 512 + col]);
        if (MODE != 2) v = v > 0.f ? v : 0.f;
        out[(size_t)m * 512 + col] = f2b(v);
      }
    }
  }
}

// Generic fp32 -> bf16 stream (8 elems/thread).
__global__ void cvt_f32_to_bf16(const float* __restrict__ src, u16* __restrict__ dst, int n8) {
  int i = blockIdx.x * blockDim.x + threadIdx.x;
  if (i >= n8) return;
  const float4* s = (const float4*)src;
  float4 a = s[2 * i], b = s[2 * i + 1];
  union { __hip_bfloat162 h[4]; bf16x8 v; } o;
  o.h[0] = __float22bfloat162_rn({a.x, a.y});
  o.h[1] = __float22bfloat162_rn({a.z, a.w});
  o.h[2] = __float22bfloat162_rn({b.x, b.y});
  o.h[3] = __float22bfloat162_rn({b.z, b.w});
  *(bf16x8*)(dst + (size_t)i * 8) = o.v;
}

// One launch: convert W_u (512x256) and W_h (512x1536) fp32 -> bf16.
__global__ void cvt_weights(const float* __restrict__ Wu,
                            const float* __restrict__ Wh,
                            u16* __restrict__ Wub, u16* __restrict__ Whb) {
  const int nWu = 512 * 256 / 8;
  const int nWh = 512 * 1536 / 8;
  int i = blockIdx.x * blockDim.x + threadIdx.x;
  const float* src; u16* dst; int c;
  if (i < nWu) { src = Wu; dst = Wub; c = i; }
  else if (i < nWu + nWh) { src = Wh; dst = Whb; c = i - nWu; }
  else return;
  const float4* s = (const float4*)(src + (size_t)c * 8);
  float4 a = s[0], b = s[1];
  union { __hip_bfloat162 h[4]; bf16x8 v; } o;
  o.h[0] = __float22bfloat162_rn({a.x, a.y});
  o.h[1] = __float22bfloat162_rn({a.z, a.w});
  o.h[2] = __float22bfloat162_rn({b.x, b.y});
  o.h[3] = __float22bfloat162_rn({b.z, b.w});
  *(bf16x8*)(dst + (size_t)c * 8) = o.v;
}

__global__ void cvt_bf16_to_f32(const u16* __restrict__ src, float* __restrict__ dst, int n4) {
  int i = blockIdx.x * blockDim.x + threadIdx.x;
  if (i >= n4) return;
  uint2 p = ((const uint2*)src)[i];
  float4 o;
  o.x = b2f(p.x & 0xffffu); o.y = b2f(p.x >> 16);
  o.z = b2f(p.y & 0xffffu); o.w = b2f(p.y >> 16);
  ((float4*)dst)[i] = o;
}

extern "C" void kernel_launch(void* const* d_in, const int* in_sizes, int n_in,
                              void* d_out, int out_size, void* d_ws, size_t ws_size,
                              hipStream_t stream) {
  const float* contents = (const float*)d_in[0];
  const int2*  children = (const int2*)d_in[1];
  const float* W_u = (const float*)d_in[2];
  const float* b_u = (const float*)d_in[3];
  const float* W_h = (const float*)d_in[4];
  const float* b_h = (const float*)d_in[5];
  float* out = (float*)d_out;

  const int B = 64, D = 11, F = 256, H = 512;
  const int N = B * ((1 << D) - 1);            // 131008
  const int NI = B * ((1 << (D - 1)) - 1);     // 65472

  // Workspace (u16 elems): u_bf [N*512] | C [N*F = 33.55M] | Wub | Whb.
  // C holds contents_bf16 during GEMM1, then v (NI*512 = 33.52M) after.
  // emb ping-pong aliases u's internal rows (dead after the v-GEMM).
  u16* ws16 = (u16*)d_ws;
  u16* u_bf = ws16;
  u16* C    = ws16 + (size_t)N * H;
  u16* Wub  = C + (size_t)N * F;
  u16* Whb  = Wub + 512 * 256;
  u16* cont_bf = C;
  u16* v_bf    = C;
  u16* embA = u_bf;                            // level-9 dst (32768 rows)
  u16* embB = u_bf + (size_t)32768 * 512;      // rows 32768.. (internal, dead)

  // --- conversions ---
  {
    int n = (512 * 256 + 512 * 1536) / 8;
    cvt_weights<<<(n + 255) / 256, 256, 0, stream>>>(W_u, W_h, Wub, Whb);
    int n8 = N * F / 8;
    cvt_f32_to_bf16<<<(n8 + 255) / 256, 256, 0, stream>>>(contents, cont_bf, n8);
  }

  // --- GEMM1: u = relu(cont_bf @ W_u^T + b_u) ---
  gemm_reg<0><<<(N / 64) * 2, 256, 0, stream>>>(cont_bf, nullptr, nullptr,
                                                nullptr, Wub, F, b_u, u_bf, N, F);

  // --- v-GEMM: v = u[0:NI] @ W_hu^T (W_h cols 1024..1535 in place) ---
  gemm_reg<2><<<(NI / 64) * 2, 256, 0, stream>>>(u_bf, nullptr, nullptr,
                                                 nullptr, Whb + 1024, 3 * H,
                                                 nullptr, v_bf, NI, H);

  // --- tree levels j = D-2 .. 0 (K=1024 children; v in epilogue) ---
  const u16* embPrev = u_bf + (size_t)NI * H;  // leaves = u[NI:]
  u16* dst = embA;
  for (int j = D - 2; j >= 0; --j) {
    int M = B << j;
    int o = B * ((1 << j) - 1);
    gemm_reg<1><<<(M / 64) * 2, 256, 0, stream>>>(nullptr, embPrev, children + o,
                                                  v_bf + (size_t)o * H,
                                                  Whb, 3 * H, b_h, dst, M, 2 * H);
    embPrev = dst;
    dst = (dst == embA) ? embB : embA;
  }

  // --- level-0 emb (64 x 512) -> fp32 output ---
  {
    int n4 = B * H / 4;
    cvt_bf16_to_f32<<<(n4 + 255) / 256, 256, 0, stream>>>(embPrev, out, n4);
  }
}